// Round 3
// baseline (26.730 us; speedup 1.0000x reference)
//
#include <hip/hip_runtime.h>

// CurvatureTotal: 3x3 stencil derivatives + fused curvature formula.
// z: (8,1,1024,1024) fp32 -> out same shape fp32.
// Cp*Ct simplifies: pow(og,1.5)*sqrt(og) = og^2, so
//   out = (numCp*numCt) / (denom_g * og)^2   -- no sqrt/pow needed.
// R1/R2: 4x vectorization along x — 16B row loads + 2 edge scalars per row,
// 4 outputs/thread, 16B nontemporal store. One 256-thread block = one row.
// (R2 fix: use clang ext_vector_type, not HIP float4 struct, for the
//  nontemporal builtin.)

namespace {

constexpr int W = 1024;
constexpr int H = 1024;
constexpr int NPLANES = 8;
constexpr float H_RES = 30.0f;
constexpr float EPS = 1e-12f;

typedef float f32x4 __attribute__((ext_vector_type(4)));

__global__ __launch_bounds__(256) void curv_kernel(const float* __restrict__ z,
                                                   float* __restrict__ out) {
    const int tid = threadIdx.x;
    const int x4 = tid * 4;                 // 256 threads * 4 = 1024 = W
    const int y = blockIdx.x;
    const size_t plane = (size_t)blockIdx.y * (size_t)(W * H);
    const float* __restrict__ zp = z + plane;

    const bool wy0 = (y > 0), wy1 = (y < H - 1);
    const int ym = wy0 ? y - 1 : 0;
    const int yp = wy1 ? y + 1 : H - 1;

    const float* __restrict__ rm = zp + (size_t)ym * W;
    const float* __restrict__ rc = zp + (size_t)y  * W;
    const float* __restrict__ rp = zp + (size_t)yp * W;

    const int xl = (x4 > 0) ? x4 - 1 : 0;           // replicate-clamped
    const int xr = (x4 + 4 < W) ? x4 + 4 : W - 1;

    const f32x4 vm = *(const f32x4*)(rm + x4);
    const f32x4 vc = *(const f32x4*)(rc + x4);
    const f32x4 vp = *(const f32x4*)(rp + x4);

    // 6-wide windows per row: [left, v0, v1, v2, v3, right]
    float mrow[6] = {rm[xl], vm.x, vm.y, vm.z, vm.w, rm[xr]};
    float crow[6] = {rc[xl], vc.x, vc.y, vc.z, vc.w, rc[xr]};
    float prow[6] = {rp[xl], vp.x, vp.y, vp.z, vp.w, rp[xr]};

    const float inv2h  = 1.0f / (2.0f * H_RES);
    const float invh2  = 1.0f / (H_RES * H_RES);
    const float inv4h2 = 0.25f * invh2;

    f32x4 res;

#pragma unroll
    for (int j = 0; j < 4; ++j) {
        const int x = x4 + j;
        const bool wx0 = (x > 0), wx1 = (x < W - 1);

        const float zc  = crow[j + 1];
        const float zw  = crow[j];
        const float ze  = crow[j + 2];
        const float zn  = mrow[j + 1];
        const float zs  = prow[j + 1];
        const float znw = mrow[j];
        const float zne = mrow[j + 2];
        const float zsw = prow[j];
        const float zse = prow[j + 2];

        // First derivatives: replicate padding (clamped taps).
        const float p = (ze - zw) * inv2h;
        const float q = (zs - zn) * inv2h;

        // Second derivatives: zero padding (mask out-of-bounds taps to 0).
        const float zwz  = wx0 ? zw : 0.0f;
        const float zez  = wx1 ? ze : 0.0f;
        const float znz  = wy0 ? zn : 0.0f;
        const float zsz  = wy1 ? zs : 0.0f;
        const float znwz = (wy0 && wx0) ? znw : 0.0f;
        const float znez = (wy0 && wx1) ? zne : 0.0f;
        const float zswz = (wy1 && wx0) ? zsw : 0.0f;
        const float zsez = (wy1 && wx1) ? zse : 0.0f;

        const float r = (zez - 2.0f * zc + zwz) * invh2;       // d2/dx2
        const float t = (zsz - 2.0f * zc + znz) * invh2;       // d2/dy2
        const float s = (znwz - znez - zswz + zsez) * inv4h2;  // d2/dxdy

        const float p2 = p * p, q2 = q * q, pq = p * q;
        const float denom_g = p2 + q2 + EPS;
        const float og      = 1.0f + p2 + q2 + EPS;

        const float numCp = p2 * r + 2.0f * pq * s + q2 * t;
        const float numCt = q2 * r - 2.0f * pq * s + p2 * t;

        const float dn  = denom_g * og;
        const float rdn = __builtin_amdgcn_rcpf(dn);   // v_rcp_f32, ~1 ulp
        res[j] = (numCp * numCt) * (rdn * rdn);
    }

    __builtin_nontemporal_store(res, (f32x4*)(out + plane + (size_t)y * W + x4));
}

}  // namespace

extern "C" void kernel_launch(void* const* d_in, const int* in_sizes, int n_in,
                              void* d_out, int out_size, void* d_ws, size_t ws_size,
                              hipStream_t stream) {
    const float* z = (const float*)d_in[0];
    float* out = (float*)d_out;
    dim3 grid(H, NPLANES, 1);
    dim3 block(256, 1, 1);
    curv_kernel<<<grid, block, 0, stream>>>(z, out);
}

// Round 4
// 16.556 us; speedup vs baseline: 1.6146x; 1.6146x over previous
//
#include <hip/hip_runtime.h>

// CurvatureTotal: 3x3 stencil derivatives + fused curvature formula.
// z: (8,1,1024,1024) fp32 -> out same shape fp32.
// Cp*Ct simplifies: pow(og,1.5)*sqrt(og) = og^2, so
//   out = (numCp*numCt) / (denom_g * og)^2   -- no sqrt/pow needed.
// R4: 4-row y-tile per thread (6 row-windows -> 4 output rows, 1.5x read amp)
//     + chunked XCD swizzle (each XCD owns one full plane -> strip overlap
//     served by its own L2; L3/HBM read ~= ideal 33.5 MB).

namespace {

constexpr int W = 1024;
constexpr int H = 1024;
constexpr int NPLANES = 8;
constexpr int ROWS = 4;                       // output rows per block
constexpr int STRIPS = H / ROWS;              // 256 strips per plane
constexpr int NWG = STRIPS * NPLANES;         // 2048 blocks
constexpr float H_RES = 30.0f;
constexpr float EPS = 1e-12f;

typedef float f32x4 __attribute__((ext_vector_type(4)));

__global__ __launch_bounds__(256) void curv_kernel(const float* __restrict__ z,
                                                   float* __restrict__ out) {
    // Chunked XCD swizzle: wgid%8 = XCD (round-robin dispatch), give each
    // XCD a contiguous chunk of NWG/8 = 256 strips = exactly one plane.
    const int wgid = blockIdx.x;
    const int swz = (wgid & 7) * (NWG / 8) + (wgid >> 3);
    const int plane_i = swz >> 8;             // / STRIPS
    const int strip   = swz & (STRIPS - 1);

    const int tid = threadIdx.x;
    const int x4 = tid * 4;                   // 256 threads * 4 = 1024 = W
    const int y0 = strip * ROWS;
    const size_t plane = (size_t)plane_i * (size_t)(W * H);
    const float* __restrict__ zp = z + plane;

    const int xl = (x4 > 0) ? x4 - 1 : 0;             // replicate-clamped
    const int xr = (x4 + 4 < W) ? x4 + 4 : W - 1;

    // 6 row-windows of 6 floats: [left, v0, v1, v2, v3, right]
    float win[ROWS + 2][6];
#pragma unroll
    for (int i = 0; i < ROWS + 2; ++i) {
        int g = y0 - 1 + i;
        g = (g < 0) ? 0 : ((g > H - 1) ? H - 1 : g);  // replicate-clamped row
        const float* __restrict__ row = zp + (size_t)g * W;
        const f32x4 v = *(const f32x4*)(row + x4);
        win[i][0] = row[xl];
        win[i][1] = v.x; win[i][2] = v.y; win[i][3] = v.z; win[i][4] = v.w;
        win[i][5] = row[xr];
    }

    const float inv2h  = 1.0f / (2.0f * H_RES);
    const float invh2  = 1.0f / (H_RES * H_RES);
    const float inv4h2 = 0.25f * invh2;

#pragma unroll
    for (int k = 0; k < ROWS; ++k) {
        const int y = y0 + k;
        const bool wy0 = (y > 0), wy1 = (y < H - 1);
        const float* mrow = win[k];
        const float* crow = win[k + 1];
        const float* prow = win[k + 2];

        f32x4 res;
#pragma unroll
        for (int j = 0; j < 4; ++j) {
            const int x = x4 + j;
            const bool wx0 = (x > 0), wx1 = (x < W - 1);

            const float zc  = crow[j + 1];
            const float zw  = crow[j];
            const float ze  = crow[j + 2];
            const float zn  = mrow[j + 1];
            const float zs  = prow[j + 1];
            const float znw = mrow[j];
            const float zne = mrow[j + 2];
            const float zsw = prow[j];
            const float zse = prow[j + 2];

            // First derivatives: replicate padding (clamped taps).
            const float p = (ze - zw) * inv2h;
            const float q = (zs - zn) * inv2h;

            // Second derivatives: zero padding (mask OOB taps to 0).
            const float zwz  = wx0 ? zw : 0.0f;
            const float zez  = wx1 ? ze : 0.0f;
            const float znz  = wy0 ? zn : 0.0f;
            const float zsz  = wy1 ? zs : 0.0f;
            const float znwz = (wy0 && wx0) ? znw : 0.0f;
            const float znez = (wy0 && wx1) ? zne : 0.0f;
            const float zswz = (wy1 && wx0) ? zsw : 0.0f;
            const float zsez = (wy1 && wx1) ? zse : 0.0f;

            const float r = (zez - 2.0f * zc + zwz) * invh2;       // d2/dx2
            const float t = (zsz - 2.0f * zc + znz) * invh2;       // d2/dy2
            const float s = (znwz - znez - zswz + zsez) * inv4h2;  // d2/dxdy

            const float p2 = p * p, q2 = q * q, pq = p * q;
            const float denom_g = p2 + q2 + EPS;
            const float og      = 1.0f + p2 + q2 + EPS;

            const float numCp = p2 * r + 2.0f * pq * s + q2 * t;
            const float numCt = q2 * r - 2.0f * pq * s + p2 * t;

            const float dn  = denom_g * og;
            const float rdn = __builtin_amdgcn_rcpf(dn);   // v_rcp_f32
            res[j] = (numCp * numCt) * (rdn * rdn);
        }

        __builtin_nontemporal_store(
            res, (f32x4*)(out + plane + (size_t)y * W + x4));
    }
}

}  // namespace

extern "C" void kernel_launch(void* const* d_in, const int* in_sizes, int n_in,
                              void* d_out, int out_size, void* d_ws, size_t ws_size,
                              hipStream_t stream) {
    const float* z = (const float*)d_in[0];
    float* out = (float*)d_out;
    dim3 grid(NWG, 1, 1);
    dim3 block(256, 1, 1);
    curv_kernel<<<grid, block, 0, stream>>>(z, out);
}